// Round 22
// baseline (601.391 us; speedup 1.0000x reference)
//
#include <hip/hip_runtime.h>
#include <math.h>

#define NNODES 20000
#define NPAD   20096   // 157 * 128
#define NEDGES 160000
#define HIDDIM 128
#define NHEADS 8
#define NGRAPH 64
#define KC 384   // concatenated K (hi | lo | hi)
#define GXTILES 157

typedef short short8 __attribute__((ext_vector_type(8)));
typedef float floatx4 __attribute__((ext_vector_type(4)));
typedef unsigned short ushort4v __attribute__((ext_vector_type(4)));

__device__ inline unsigned short f2bf(float x) {
    unsigned u = __float_as_uint(x);
    u += 0x7fff + ((u >> 16) & 1);
    return (unsigned short)(u >> 16);
}
__device__ inline float bf2f(unsigned short h) {
    return __uint_as_float(((unsigned)h) << 16);
}

// ---------------- utility ----------------
__global__ __launch_bounds__(256) void zero_kernel(float* __restrict__ p, int n) {
    int i = blockIdx.x * blockDim.x + threadIdx.x;
    if (i < n) p[i] = 0.f;
}

// ---------------- CSR build ----------------
__global__ __launch_bounds__(256) void count_deg_kernel(const int* __restrict__ dst,
                                                        int* __restrict__ deg, int e) {
    int i = blockIdx.x * blockDim.x + threadIdx.x;
    if (i < e) atomicAdd(&deg[dst[i]], 1);
}

__global__ __launch_bounds__(256) void scan1_kernel(const int* __restrict__ deg,
                                                    int* __restrict__ chunk,
                                                    int* __restrict__ bsum, int n) {
    __shared__ int buf[256];
    int t = threadIdx.x;
    int i = blockIdx.x * 256 + t;
    int v = (i < n) ? deg[i] : 0;
    buf[t] = v;
    __syncthreads();
    for (int off = 1; off < 256; off <<= 1) {
        int tmp = (t >= off) ? buf[t - off] : 0;
        __syncthreads();
        buf[t] += tmp;
        __syncthreads();
    }
    if (i < n) chunk[i] = buf[t];
    if (t == 255) bsum[blockIdx.x] = buf[255];
}

__global__ __launch_bounds__(128) void scan2_kernel(int* __restrict__ bsum, int nb) {
    __shared__ int buf[128];
    int t = threadIdx.x;
    int v = (t < nb) ? bsum[t] : 0;
    buf[t] = v;
    __syncthreads();
    for (int off = 1; off < 128; off <<= 1) {
        int tmp = (t >= off) ? buf[t - off] : 0;
        __syncthreads();
        buf[t] += tmp;
        __syncthreads();
    }
    if (t < nb) bsum[t] = buf[t] - v;
}

__global__ __launch_bounds__(256) void scan3_kernel(const int* __restrict__ chunk,
                                                    const int* __restrict__ bsum,
                                                    int* __restrict__ offs, int n) {
    int i = blockIdx.x * 256 + threadIdx.x;
    if (i < n) offs[i + 1] = chunk[i] + bsum[i >> 8];
    if (i == 0) offs[0] = 0;
}

__global__ __launch_bounds__(256) void scatter_kernel(const int* __restrict__ src,
                                                      const int* __restrict__ dst,
                                                      const int* __restrict__ offs,
                                                      int* __restrict__ cursor,
                                                      int* __restrict__ csr_src, int e) {
    int i = blockIdx.x * blockDim.x + threadIdx.x;
    if (i < e) {
        int d = dst[i];
        int pos = offs[d] + atomicAdd(&cursor[d], 1);
        csr_src[pos] = src[i];
    }
}

// ---------------- weight prep ----------------
// Rows: [0,1536) layers 0-2 q|k|v|s (li*512 + sel*128 + j) ; [1536,1664) Wp ;
// [1664,2688) layer3 t rows (mqk fills) ; [2688,2816) layer3 s rows (Ws3).
__global__ __launch_bounds__(128) void prep_w_kernel(
    const float* __restrict__ Wq, const float* __restrict__ Wk,
    const float* __restrict__ Wv, const float* __restrict__ Ws,
    const float* __restrict__ Wp, const float* __restrict__ Ws3,
    unsigned short* __restrict__ WtAll) {
    int id = blockIdx.x;
    int k = threadIdx.x;
    float w;
    if (id < 1536) {
        int li = id / 512, n = id % 512, sel = n >> 7, np = n & 127;
        const float* W = (sel == 0) ? Wq : (sel == 1) ? Wk : (sel == 2) ? Wv : Ws;
        w = W[li * 16384 + k * 128 + np];
    } else if (id < 1664) {
        w = Wp[k * 128 + (id - 1536)];
    } else if (id < 2688) {
        return;  // t rows: filled by mqk_kernel
    } else {
        w = Ws3[k * 128 + (id - 2688)];
    }
    unsigned short hi = f2bf(w);
    unsigned short lo = f2bf(w - bf2f(hi));
    unsigned short* dst = WtAll + (size_t)id * KC;
    dst[k] = hi;
    dst[128 + k] = hi;
    dst[256 + k] = lo;
}

__global__ __launch_bounds__(256) void prep_bias_kernel(
    const float* __restrict__ bq, const float* __restrict__ bk,
    const float* __restrict__ bv, const float* __restrict__ bs,
    const float* __restrict__ bs3, float* __restrict__ bcat) {
    int id = blockIdx.x * 256 + threadIdx.x;
    if (id >= 2688) return;
    float v;
    if (id < 1536) {
        int li = id / 512, n = id % 512, sel = n >> 7, np = n & 127;
        const float* b = (sel == 0) ? bq : (sel == 1) ? bk : (sel == 2) ? bv : bs;
        v = b[li * 128 + np];
    } else if (id < 2560) {
        return;  // t bias: mqk fills
    } else {
        v = bs3[id - 2560];
    }
    bcat[id] = v;
}

// ---------------- layer-3 fused QK weights: M_h = Wq_h Wk_h^T ----------------
__global__ __launch_bounds__(128) void mqk_kernel(
    const float* __restrict__ Wq3, const float* __restrict__ Wk3,
    const float* __restrict__ bq3,
    unsigned short* __restrict__ WtAll, float* __restrict__ bcat) {
    int hb = blockIdx.x;
    int h = hb >> 7, b = hb & 127;
    int a = threadIdx.x;
    __shared__ float wk[128];
    wk[a] = Wk3[(size_t)b * 1024 + h * 128 + a];
    __syncthreads();
    const float* wq = Wq3 + (size_t)a * 1024 + h * 128;
    float acc = 0.f;
#pragma unroll 16
    for (int d = 0; d < 128; ++d) acc = fmaf(wq[d], wk[d], acc);
    unsigned short hi = f2bf(acc);
    unsigned short lo = f2bf(acc - bf2f(hi));
    unsigned short* dst = WtAll + (size_t)(1664 + h * 128 + b) * KC;
    dst[a] = hi;
    dst[128 + a] = hi;
    dst[256 + a] = lo;
    if (a == 0) {
        float bb = 0.f;
        for (int d = 0; d < 128; ++d) bb = fmaf(bq3[h * 128 + d], wk[d], bb);
        bcat[1536 + h * 128 + b] = bb;
    }
}

// ---------------- mean-V weights: Wvm[j][h*128+a] = Wv3[a][h*128+j]/8 ----------------
__global__ __launch_bounds__(128) void prep_wvm_kernel(
    const float* __restrict__ Wv3, const float* __restrict__ bv3,
    unsigned short* __restrict__ Wvm, float* __restrict__ bvm) {
    int j = blockIdx.x;
    int a = threadIdx.x;
#pragma unroll
    for (int h = 0; h < 8; ++h) {
        float w = Wv3[(size_t)a * 1024 + h * 128 + j] * 0.125f;
        Wvm[(size_t)j * 1024 + h * 128 + a] = f2bf(w);
    }
    if (a == 0) {
        float s = 0.f;
        for (int h = 0; h < 8; ++h) s += bv3[h * 128 + j];
        bvm[j] = s * 0.125f;
    }
}

// ---------------- activation -> split-bf16 A_cat ----------------
__global__ __launch_bounds__(256) void cat_from_kernel(const float* __restrict__ h,
                                                       unsigned short* __restrict__ Acat) {
    int idx = blockIdx.x * 256 + threadIdx.x;
    if (idx >= NPAD * HIDDIM) return;
    int r = idx >> 7, k = idx & 127;
    float x = (r < NNODES) ? h[idx] : 0.f;
    unsigned short hi = f2bf(x);
    unsigned short lo = f2bf(x - bf2f(hi));
    unsigned short* row = Acat + (size_t)r * KC;
    row[k] = hi;
    row[128 + k] = lo;
    row[256 + k] = hi;
}

// ---------------- MFMA GEMM (XCD swizzle; double-buffered fragments) ----------------
// CATOUT=1: OutT must be ushort; writes split-bf16 rows of Acat (stride KC).
template <typename OutT, int KG, int BY, int CATOUT>
__global__ __launch_bounds__(256) void gemm_mfma_kernel(
    const unsigned short* __restrict__ Acat, const unsigned short* __restrict__ Wt,
    const float* __restrict__ bias, OutT* __restrict__ C, int M, int nrows) {
    int id = blockIdx.x;
    int xcd = id & 7;
    int idx = id >> 3;
    int bx = (idx / BY) * 8 + xcd;
    int by = idx % BY;
    if (bx >= GXTILES) return;
    int lane = threadIdx.x & 63;
    int wave = threadIdx.x >> 6;
    int nodeBase = bx * 128 + (wave & 1) * 64;
    int featBase = by * 128 + (wave >> 1) * 64;
    int m = lane & 15;
    int q = lane >> 4;
    int ko = q * 8;
    const unsigned short* wptr = Wt + (size_t)(featBase + m) * KC + ko;
    const unsigned short* aptr = Acat + (size_t)(nodeBase + m) * KC + ko;
    floatx4 acc[4][4];
#pragma unroll
    for (int r = 0; r < 4; ++r)
#pragma unroll
        for (int c = 0; c < 4; ++c) acc[r][c] = (floatx4){0.f, 0.f, 0.f, 0.f};
    short8 a[2][4], b[2][4];
#pragma unroll
    for (int r = 0; r < 4; ++r) a[0][r] = *(const short8*)(wptr + (size_t)r * 16 * KC);
#pragma unroll
    for (int c = 0; c < 4; ++c) b[0][c] = *(const short8*)(aptr + (size_t)c * 16 * KC);
#pragma unroll
    for (int kg = 0; kg < KG; ++kg) {
        int cur = kg & 1, nxt = cur ^ 1;
        if (kg + 1 < KG) {
#pragma unroll
            for (int r = 0; r < 4; ++r)
                a[nxt][r] = *(const short8*)(wptr + (size_t)r * 16 * KC + (kg + 1) * 32);
#pragma unroll
            for (int c = 0; c < 4; ++c)
                b[nxt][c] = *(const short8*)(aptr + (size_t)c * 16 * KC + (kg + 1) * 32);
        }
#pragma unroll
        for (int r = 0; r < 4; ++r)
#pragma unroll
            for (int c = 0; c < 4; ++c)
                acc[r][c] = __builtin_amdgcn_mfma_f32_16x16x32_bf16(a[cur][r], b[cur][c],
                                                                   acc[r][c], 0, 0, 0);
    }
    float4 bv[4];
#pragma unroll
    for (int r = 0; r < 4; ++r) bv[r] = *(const float4*)(bias + featBase + r * 16 + q * 4);
#pragma unroll
    for (int c = 0; c < 4; ++c) {
        int node = nodeBase + c * 16 + m;
        if (node < nrows) {
#pragma unroll
            for (int r = 0; r < 4; ++r) {
                int f0 = featBase + r * 16 + q * 4;
                float v0 = acc[r][c][0] + bv[r].x;
                float v1 = acc[r][c][1] + bv[r].y;
                float v2 = acc[r][c][2] + bv[r].z;
                float v3 = acc[r][c][3] + bv[r].w;
                if (CATOUT) {
                    unsigned short h0 = f2bf(v0), h1 = f2bf(v1), h2 = f2bf(v2), h3 = f2bf(v3);
                    ushort4v hi = {h0, h1, h2, h3};
                    ushort4v lo = {f2bf(v0 - bf2f(h0)), f2bf(v1 - bf2f(h1)),
                                   f2bf(v2 - bf2f(h2)), f2bf(v3 - bf2f(h3))};
                    unsigned short* row = (unsigned short*)C + (size_t)node * KC;
                    *(ushort4v*)(row + f0) = hi;
                    *(ushort4v*)(row + 128 + f0) = lo;
                    *(ushort4v*)(row + 256 + f0) = hi;
                } else if (sizeof(OutT) == 2) {
                    ushort4v o = {f2bf(v0), f2bf(v1), f2bf(v2), f2bf(v3)};
                    *(ushort4v*)((unsigned short*)C + (size_t)node * M + f0) = o;
                } else {
                    float4 o = {v0, v1, v2, v3};
                    *(float4*)((float*)C + (size_t)node * M + f0) = o;
                }
            }
        }
    }
}

// ---------------- mean-V GEMM: omean[N][128] = agg[N][1024] @ Wvm^T + bvm ----------------
__global__ __launch_bounds__(256) void gemm_vmean_kernel(
    const unsigned short* __restrict__ agg, const unsigned short* __restrict__ Wvm,
    const float* __restrict__ bvm, float* __restrict__ omean, int nrows) {
    int id = blockIdx.x;
    int xcd = id & 7;
    int idx = id >> 3;
    int bx = idx * 8 + xcd;
    if (bx >= GXTILES) return;
    int lane = threadIdx.x & 63;
    int wave = threadIdx.x >> 6;
    int nodeBase = bx * 128 + (wave & 1) * 64;
    int featHalf = (wave >> 1) * 64;
    int m = lane & 15;
    int q = lane >> 4;
    const unsigned short* wptr = Wvm + (size_t)(featHalf + m) * 1024 + q * 8;
    const unsigned short* aptr = agg + (size_t)(nodeBase + m) * 1024 + q * 8;
    floatx4 acc[4][4];
#pragma unroll
    for (int r = 0; r < 4; ++r)
#pragma unroll
        for (int c = 0; c < 4; ++c) acc[r][c] = (floatx4){0.f, 0.f, 0.f, 0.f};
#pragma unroll
    for (int kg = 0; kg < 32; ++kg) {
        short8 a[4], b[4];
#pragma unroll
        for (int r = 0; r < 4; ++r) a[r] = *(const short8*)(wptr + (size_t)r * 16 * 1024 + kg * 32);
#pragma unroll
        for (int c = 0; c < 4; ++c) b[c] = *(const short8*)(aptr + (size_t)c * 16 * 1024 + kg * 32);
#pragma unroll
        for (int r = 0; r < 4; ++r)
#pragma unroll
            for (int c = 0; c < 4; ++c)
                acc[r][c] = __builtin_amdgcn_mfma_f32_16x16x32_bf16(a[r], b[c], acc[r][c], 0, 0, 0);
    }
    float4 bv[4];
#pragma unroll
    for (int r = 0; r < 4; ++r) bv[r] = *(const float4*)(bvm + featHalf + r * 16 + q * 4);
#pragma unroll
    for (int c = 0; c < 4; ++c) {
        int node = nodeBase + c * 16 + m;
        if (node < nrows) {
#pragma unroll
            for (int r = 0; r < 4; ++r) {
                int f0 = featHalf + r * 16 + q * 4;
                float4 o = {acc[r][c][0] + bv[r].x, acc[r][c][1] + bv[r].y,
                            acc[r][c][2] + bv[r].z, acc[r][c][3] + bv[r].w};
                *(float4*)(omean + (size_t)node * HIDDIM + f0) = o;
            }
        }
    }
}

// ---------------- attention layers 0-2 (plain-exp; qkvs bf16 [N][512]) ----------------
__global__ __launch_bounds__(64) void attn_small_kernel(
    const unsigned short* __restrict__ qkvs,
    const float* __restrict__ Wb,
    const int* __restrict__ offs, const int* __restrict__ csr_src,
    float* __restrict__ out) {
    int i = blockIdx.x;
    int l = threadIdx.x;
    int g = l >> 5;
    int d0 = (l & 31) * 4;
    uint2 qraw = *(const uint2*)(qkvs + (size_t)i * 512 + d0);
    float q0 = bf2f((unsigned short)(qraw.x & 0xffff)), q1 = bf2f((unsigned short)(qraw.x >> 16));
    float q2 = bf2f((unsigned short)(qraw.y & 0xffff)), q3 = bf2f((unsigned short)(qraw.y >> 16));
    int e0 = offs[i], e1 = offs[i + 1];
    float lac = 0.f;
    float a0 = 0.f, a1 = 0.f, a2 = 0.f, a3 = 0.f;
    for (int e = e0 + g; e < e1; e += 2) {
        int sn = csr_src[e];
        const unsigned short* row = qkvs + (size_t)sn * 512;
        uint2 kk = *(const uint2*)(row + 128 + d0);
        uint2 vv = *(const uint2*)(row + 256 + d0);
        float k0 = bf2f((unsigned short)(kk.x & 0xffff)), k1 = bf2f((unsigned short)(kk.x >> 16));
        float k2 = bf2f((unsigned short)(kk.y & 0xffff)), k3 = bf2f((unsigned short)(kk.y >> 16));
        float p = q0 * k0 + q1 * k1 + q2 * k2 + q3 * k3;
        p += __shfl_xor(p, 1);
        p += __shfl_xor(p, 2);
        float w = __expf(p * 0.25f);
        float v0 = bf2f((unsigned short)(vv.x & 0xffff)), v1 = bf2f((unsigned short)(vv.x >> 16));
        float v2 = bf2f((unsigned short)(vv.y & 0xffff)), v3 = bf2f((unsigned short)(vv.y >> 16));
        a0 += w * v0;
        a1 += w * v1;
        a2 += w * v2;
        a3 += w * v3;
        lac += w;
    }
    a0 += __shfl_xor(a0, 32);
    a1 += __shfl_xor(a1, 32);
    a2 += __shfl_xor(a2, 32);
    a3 += __shfl_xor(a3, 32);
    lac += __shfl_xor(lac, 32);
    float inv = 1.f / (lac + 1e-16f);
    float o0 = a0 * inv, o1 = a1 * inv, o2 = a2 * inv, o3 = a3 * inv;
    uint2 rraw = *(const uint2*)(qkvs + (size_t)i * 512 + 384 + d0);
    float r0 = bf2f((unsigned short)(rraw.x & 0xffff)), r1 = bf2f((unsigned short)(rraw.x >> 16));
    float r2 = bf2f((unsigned short)(rraw.y & 0xffff)), r3 = bf2f((unsigned short)(rraw.y >> 16));
    float part = o0 * Wb[d0] + o1 * Wb[d0 + 1] + o2 * Wb[d0 + 2] + o3 * Wb[d0 + 3]
               + r0 * Wb[128 + d0] + r1 * Wb[128 + d0 + 1]
               + r2 * Wb[128 + d0 + 2] + r3 * Wb[128 + d0 + 3]
               + (o0 - r0) * Wb[256 + d0] + (o1 - r1) * Wb[256 + d0 + 1]
               + (o2 - r2) * Wb[256 + d0 + 2] + (o3 - r3) * Wb[256 + d0 + 3];
    if (g) part = 0.f;
#pragma unroll
    for (int msk = 1; msk <= 32; msk <<= 1) part += __shfl_xor(part, msk);
    float gg = 1.f / (1.f + __expf(-part));
    if (g == 0) {
        float4 o4 = {gg * r0 + (1.f - gg) * o0, gg * r1 + (1.f - gg) * o1,
                     gg * r2 + (1.f - gg) * o2, gg * r3 + (1.f - gg) * o3};
        *(float4*)(out + (size_t)i * HIDDIM + d0) = o4;
    }
}

// ---------------- attention layer 3: ALL 8 heads in one block ----------------
__global__ __launch_bounds__(64) void attn_big_kernel(
    const unsigned short* __restrict__ tbuf, const unsigned short* __restrict__ Acat,
    const int* __restrict__ offs, const int* __restrict__ csr_src,
    unsigned short* __restrict__ agg) {
    int i = blockIdx.x;
    int l = threadIdx.x;
    int doff = (l & 7) * 16;
    const unsigned short* tp = tbuf + (size_t)i * 1152 + l * 16;
    uint4 t0 = *(const uint4*)tp;
    uint4 t1 = *(const uint4*)(tp + 8);
    float tq[16];
    tq[0] = bf2f((unsigned short)(t0.x & 0xffff)); tq[1] = bf2f((unsigned short)(t0.x >> 16));
    tq[2] = bf2f((unsigned short)(t0.y & 0xffff)); tq[3] = bf2f((unsigned short)(t0.y >> 16));
    tq[4] = bf2f((unsigned short)(t0.z & 0xffff)); tq[5] = bf2f((unsigned short)(t0.z >> 16));
    tq[6] = bf2f((unsigned short)(t0.w & 0xffff)); tq[7] = bf2f((unsigned short)(t0.w >> 16));
    tq[8] = bf2f((unsigned short)(t1.x & 0xffff)); tq[9] = bf2f((unsigned short)(t1.x >> 16));
    tq[10] = bf2f((unsigned short)(t1.y & 0xffff)); tq[11] = bf2f((unsigned short)(t1.y >> 16));
    tq[12] = bf2f((unsigned short)(t1.z & 0xffff)); tq[13] = bf2f((unsigned short)(t1.z >> 16));
    tq[14] = bf2f((unsigned short)(t1.w & 0xffff)); tq[15] = bf2f((unsigned short)(t1.w >> 16));
    int e0 = offs[i], e1 = offs[i + 1];
    float ac[16];
#pragma unroll
    for (int j = 0; j < 16; ++j) ac[j] = 0.f;
    float lac = 0.f;
    for (int e = e0; e < e1; ++e) {
        int sn = csr_src[e];
        const unsigned short* hp = Acat + (size_t)sn * KC + doff;
        uint4 k0 = *(const uint4*)hp;
        uint4 k1 = *(const uint4*)(hp + 8);
        float kk[16];
        kk[0] = bf2f((unsigned short)(k0.x & 0xffff)); kk[1] = bf2f((unsigned short)(k0.x >> 16));
        kk[2] = bf2f((unsigned short)(k0.y & 0xffff)); kk[3] = bf2f((unsigned short)(k0.y >> 16));
        kk[4] = bf2f((unsigned short)(k0.z & 0xffff)); kk[5] = bf2f((unsigned short)(k0.z >> 16));
        kk[6] = bf2f((unsigned short)(k0.w & 0xffff)); kk[7] = bf2f((unsigned short)(k0.w >> 16));
        kk[8] = bf2f((unsigned short)(k1.x & 0xffff)); kk[9] = bf2f((unsigned short)(k1.x >> 16));
        kk[10] = bf2f((unsigned short)(k1.y & 0xffff)); kk[11] = bf2f((unsigned short)(k1.y >> 16));
        kk[12] = bf2f((unsigned short)(k1.z & 0xffff)); kk[13] = bf2f((unsigned short)(k1.z >> 16));
        kk[14] = bf2f((unsigned short)(k1.w & 0xffff)); kk[15] = bf2f((unsigned short)(k1.w >> 16));
        float p = 0.f;
#pragma unroll
        for (int j = 0; j < 16; ++j) p = fmaf(tq[j], kk[j], p);
        p += __shfl_xor(p, 1);
        p += __shfl_xor(p, 2);
        p += __shfl_xor(p, 4);
        float w = __expf(p * 0.08838834764831845f);
#pragma unroll
        for (int j = 0; j < 16; ++j) ac[j] = fmaf(w, kk[j], ac[j]);
        lac += w;
    }
    float inv = 1.f / (lac + 1e-16f);
    unsigned short* o = agg + (size_t)i * 1024 + l * 16;
    ushort4v o0 = {f2bf(ac[0] * inv), f2bf(ac[1] * inv), f2bf(ac[2] * inv), f2bf(ac[3] * inv)};
    ushort4v o1 = {f2bf(ac[4] * inv), f2bf(ac[5] * inv), f2bf(ac[6] * inv), f2bf(ac[7] * inv)};
    ushort4v o2 = {f2bf(ac[8] * inv), f2bf(ac[9] * inv), f2bf(ac[10] * inv), f2bf(ac[11] * inv)};
    ushort4v o3 = {f2bf(ac[12] * inv), f2bf(ac[13] * inv), f2bf(ac[14] * inv), f2bf(ac[15] * inv)};
    *(ushort4v*)o = o0;
    *(ushort4v*)(o + 4) = o1;
    *(ushort4v*)(o + 8) = o2;
    *(ushort4v*)(o + 12) = o3;
}

// ---------------- beta gate layer 3 (s bf16 from tbuf offset 1024) ----------------
__global__ __launch_bounds__(128) void beta3_kernel(const float* __restrict__ omean,
                                                    const unsigned short* __restrict__ tbuf,
                                                    const float* __restrict__ Wb,
                                                    float* __restrict__ out) {
    int i = blockIdx.x, t = threadIdx.x;
    float o = omean[(size_t)i * HIDDIM + t];
    float r = bf2f(tbuf[(size_t)i * 1152 + 1024 + t]);
    float part = o * Wb[t] + r * Wb[128 + t] + (o - r) * Wb[256 + t];
#pragma unroll
    for (int msk = 1; msk <= 32; msk <<= 1) part += __shfl_xor(part, msk);
    __shared__ float wsum[2];
    if ((t & 63) == 0) wsum[t >> 6] = part;
    __syncthreads();
    float tot = wsum[0] + wsum[1];
    float g = 1.f / (1.f + __expf(-tot));
    out[(size_t)i * HIDDIM + t] = g * r + (1.f - g) * o;
}

// ---------------- batchnorm ----------------
__global__ __launch_bounds__(128) void bn_stats_kernel(const float* __restrict__ x,
                                                       float* __restrict__ stat, int n) {
    int t = threadIdx.x;
    float s = 0.f, sq = 0.f;
    for (int i = blockIdx.x; i < n; i += gridDim.x) {
        float v = x[(size_t)i * HIDDIM + t];
        s += v;
        sq += v * v;
    }
    atomicAdd(&stat[t], s);
    atomicAdd(&stat[HIDDIM + t], sq);
}

__global__ __launch_bounds__(128) void bn_apply_kernel(float* __restrict__ x,
                                                       const float* __restrict__ stat,
                                                       const float* __restrict__ gamma,
                                                       const float* __restrict__ beta, int n,
                                                       unsigned short* __restrict__ cat) {
    int t = threadIdx.x;
    float mu = stat[t] / (float)n;
    float var = stat[HIDDIM + t] / (float)n - mu * mu;
    float rs = rsqrtf(var + 1e-5f);
    float g = gamma[t], b = beta[t];
    for (int i = blockIdx.x; i < n; i += gridDim.x) {
        float v = x[(size_t)i * HIDDIM + t];
        v = fmaxf((v - mu) * rs * g + b, 0.f);
        x[(size_t)i * HIDDIM + t] = v;
        if (cat) {
            unsigned short hi = f2bf(v);
            unsigned short lo = f2bf(v - bf2f(hi));
            unsigned short* row = cat + (size_t)i * KC;
            row[t] = hi;
            row[128 + t] = lo;
            row[256 + t] = hi;
        }
    }
}

// ---------------- pool ----------------
__global__ __launch_bounds__(256) void gb_kernel(const int* __restrict__ batch,
                                                 int* __restrict__ gs,
                                                 int* __restrict__ ge, int n) {
    int i = blockIdx.x * 256 + threadIdx.x;
    if (i >= n) return;
    int b = batch[i];
    if (i == 0 || batch[i - 1] != b) gs[b] = i;
    if (i == n - 1 || batch[i + 1] != b) ge[b] = i + 1;
}

__global__ __launch_bounds__(256) void pool_part_kernel(const float* __restrict__ x,
                                                        const int* __restrict__ gs,
                                                        const int* __restrict__ ge,
                                                        float* __restrict__ out) {
    int g = blockIdx.x, c = blockIdx.y;
    int t = threadIdx.x;
    int f = t & 127, half = t >> 7;
    int s = gs[g], e = ge[g];
    float acc = 0.f;
    for (int i = s + 2 * c + half; i < e; i += 16) acc += x[(size_t)i * HIDDIM + f];
    __shared__ float l0[128];
    if (half == 0) l0[f] = acc;
    __syncthreads();
    if (half == 1) atomicAdd(&out[g * HIDDIM + f], l0[f] + acc);
}

__global__ __launch_bounds__(128) void pool_div_kernel(float* __restrict__ out,
                                                       const int* __restrict__ gs,
                                                       const int* __restrict__ ge) {
    int g = blockIdx.x, t = threadIdx.x;
    int c = ge[g] - gs[g];
    out[g * HIDDIM + t] /= (float)(c > 0 ? c : 1);
}

// ---------------- host ----------------
extern "C" void kernel_launch(void* const* d_in, const int* in_sizes, int n_in,
                              void* d_out, int out_size, void* d_ws, size_t ws_size,
                              hipStream_t stream) {
    const float* x       = (const float*)d_in[0];
    const int*   ei      = (const int*)d_in[1];
    const int*   batch   = (const int*)d_in[2];
    const float* Wp      = (const float*)d_in[3];
    const float* bp      = (const float*)d_in[4];
    const float* Wq      = (const float*)d_in[5];
    const float* bq      = (const float*)d_in[6];
    const float* Wk      = (const float*)d_in[7];
    const float* bk      = (const float*)d_in[8];
    const float* Wv      = (const float*)d_in[9];
    const float* bv      = (const float*)d_in[10];
    const float* Ws      = (const float*)d_in[11];
    const float* bs      = (const float*)d_in[12];
    const float* Wbeta   = (const float*)d_in[13];
    const float* Wq3     = (const float*)d_in[14];
    const float* bq3     = (const float*)d_in[15];
    const float* Wk3     = (const float*)d_in[16];
    const float* bk3     = (const float*)d_in[17];
    const float* Wv3     = (const float*)d_in[18];
    const float* bv3     = (const float*)d_in[19];
    const float* Ws3     = (const float*)d_in[20];
    const float* bs3     = (const float*)d_in[21];
    const float* Wbeta3  = (const float*)d_in[22];
    const float* bn_gamma = (const float*)d_in[23];
    const float* bn_beta  = (const float*)d_in[24];
    float* out = (float*)d_out;
    (void)bk3;

    const int* esrc = ei;
    const int* edst = ei + NEDGES;

    char* wpc = (char*)d_ws;
    auto alloc = [&](size_t nbytes) -> char* {
        char* p = wpc;
        wpc += (nbytes + 255) & ~(size_t)255;
        return p;
    };
    unsigned short* Acat  = (unsigned short*)alloc((size_t)NPAD * KC * 2);      // 15.4 MB
    unsigned short* WtAll = (unsigned short*)alloc((size_t)2816 * KC * 2);      // 2.2 MB
    float* bcat   = (float*)alloc(2688 * 4);
    unsigned short* Wvm   = (unsigned short*)alloc((size_t)128 * 1024 * 2);     // 256 KB
    float* bvm    = (float*)alloc(128 * 4);
    unsigned short* tbuf  = (unsigned short*)alloc((size_t)NPAD * 1152 * 2);    // 46.3 MB (alias qkvs)
    unsigned short* aggb  = (unsigned short*)alloc((size_t)NPAD * 1024 * 2);    // 41 MB
    float* omean  = (float*)alloc((size_t)NNODES * HIDDIM * 4);                 // 10.2 MB
    float* hbuf   = (float*)alloc((size_t)NNODES * HIDDIM * 4);
    float* obuf   = (float*)alloc((size_t)NNODES * HIDDIM * 4);
    int*   deg    = (int*)alloc((2 * NNODES + 128 + 4 * 256) * 4);
    int*   cursor = deg + NNODES;
    int*   gs     = deg + 2 * NNODES;
    int*   ge     = gs + NGRAPH;
    float* bnstat4 = (float*)(deg + 2 * NNODES + 128);
    int*   chunk  = (int*)alloc(NNODES * 4);
    int*   bsum   = (int*)alloc(128 * 4);
    int*   offs   = (int*)alloc((NNODES + 1) * 4);
    int*   csrsrc = (int*)alloc(NEDGES * 4);

    unsigned short* WtQKVS = WtAll;                      // [3][512][KC] q|k|v|s
    unsigned short* Wpt    = WtAll + (size_t)1536 * KC;
    unsigned short* Wt3    = WtAll + (size_t)1664 * KC;  // [1152][KC] t|s3
    float* bQKVS = bcat;          // [3][512]
    float* b3    = bcat + 1536;   // [1152] t|s3
    unsigned short* qkvs = tbuf;  // layers 0-2 alias: [N][512]

    const int TB = 256;
    const int ZWORDS = 2 * NNODES + 128 + 4 * 256;
    zero_kernel<<<(ZWORDS + TB - 1) / TB, TB, 0, stream>>>((float*)deg, ZWORDS);
    count_deg_kernel<<<(NEDGES + TB - 1) / TB, TB, 0, stream>>>(edst, deg, NEDGES);
    const int NB = (NNODES + 255) / 256;
    scan1_kernel<<<NB, 256, 0, stream>>>(deg, chunk, bsum, NNODES);
    scan2_kernel<<<1, 128, 0, stream>>>(bsum, NB);
    scan3_kernel<<<NB, 256, 0, stream>>>(chunk, bsum, offs, NNODES);
    scatter_kernel<<<(NEDGES + TB - 1) / TB, TB, 0, stream>>>(esrc, edst, offs, cursor, csrsrc, NEDGES);
    gb_kernel<<<(NNODES + TB - 1) / TB, TB, 0, stream>>>(batch, gs, ge, NNODES);

    prep_w_kernel<<<2816, 128, 0, stream>>>(Wq, Wk, Wv, Ws, Wp, Ws3, WtAll);
    prep_bias_kernel<<<(2688 + TB - 1) / TB, TB, 0, stream>>>(bq, bk, bv, bs, bs3, bcat);
    mqk_kernel<<<1024, 128, 0, stream>>>(Wq3, Wk3, bq3, WtAll, bcat);
    prep_wvm_kernel<<<128, 128, 0, stream>>>(Wv3, bv3, Wvm, bvm);

    const int CATB = (NPAD * HIDDIM + TB - 1) / TB;
    const int GSW = 8 * ((GXTILES + 7) / 8);  // 160 swizzled x-slots

    cat_from_kernel<<<CATB, TB, 0, stream>>>(x, Acat);
    // proj writes Acat split-bf16 directly (CATOUT)
    gemm_mfma_kernel<unsigned short, 12, 1, 1><<<GSW * 1, 256, 0, stream>>>(
        Acat, Wpt, bp, Acat, 128, NNODES);

    for (int li = 0; li < 3; ++li) {
        gemm_mfma_kernel<unsigned short, 8, 4, 0><<<GSW * 4, 256, 0, stream>>>(
            Acat, WtQKVS + (size_t)li * 512 * KC, bQKVS + li * 512, qkvs, 512, NNODES);
        attn_small_kernel<<<NNODES, 64, 0, stream>>>(qkvs, Wbeta + li * 384,
                                                     offs, csrsrc, obuf);
        float* st = bnstat4 + li * 256;
        bn_stats_kernel<<<640, 128, 0, stream>>>(obuf, st, NNODES);
        bn_apply_kernel<<<512, 128, 0, stream>>>(obuf, st, bn_gamma + li * HIDDIM,
                                                 bn_beta + li * HIDDIM, NNODES, Acat);
    }

    // ---- layer 3: t|s GEMM -> fused 8-head aggregate -> mean-V GEMM -> beta ----
    gemm_mfma_kernel<unsigned short, 8, 9, 0><<<GSW * 9, 256, 0, stream>>>(
        Acat, Wt3, b3, tbuf, 1152, NNODES);
    attn_big_kernel<<<NNODES, 64, 0, stream>>>(tbuf, Acat, offs, csrsrc, aggb);
    gemm_vmean_kernel<<<GSW, 256, 0, stream>>>(aggb, Wvm, bvm, omean, NNODES);
    beta3_kernel<<<NNODES, 128, 0, stream>>>(omean, tbuf, Wbeta3, hbuf);
    float* st3 = bnstat4 + 3 * 256;
    bn_stats_kernel<<<640, 128, 0, stream>>>(hbuf, st3, NNODES);
    bn_apply_kernel<<<512, 128, 0, stream>>>(hbuf, st3, bn_gamma + 3 * HIDDIM,
                                             bn_beta + 3 * HIDDIM, NNODES, (unsigned short*)0);

    zero_kernel<<<(NGRAPH * HIDDIM + TB - 1) / TB, TB, 0, stream>>>(out, NGRAPH * HIDDIM);
    pool_part_kernel<<<dim3(NGRAPH, 8), 256, 0, stream>>>(hbuf, gs, ge, out);
    pool_div_kernel<<<NGRAPH, 128, 0, stream>>>(out, gs, ge);
}